// Round 18
// 925.229 us; speedup vs baseline: 5.2571x; 1.0297x over previous
//
#include <hip/hip_runtime.h>
#include <hip/hip_bf16.h>
#include <cfloat>
#include <math.h>

typedef __hip_bfloat16 bf16;
typedef __attribute__((ext_vector_type(8))) short short8v;
typedef __attribute__((ext_vector_type(4))) float f32x4;

constexpr int B_ = 2, T_ = 24, N_ = 1500, E_ = 2000, M_ = 4000, G_ = 48;
constexpr int KPN = 2048;
constexpr int KPE = 1536;

__device__ __forceinline__ float b2f(bf16 v) { return __bfloat162float(v); }
__device__ __forceinline__ bf16 f2b(float v) { return __float2bfloat16(v); }
static inline int ceilDiv(int a, int b) { return (a + b - 1) / b; }

// ---------------- diagnostics ----------------
__global__ __launch_bounds__(256) void k_sentinel(float* __restrict__ out, int n, float val) {
  int i = blockIdx.x * 256 + threadIdx.x;
  if (i < n) out[i] = val;
}

// ---------------- device bodies for the fused prologue ----------------
__device__ __forceinline__ void wprep_body(int i, const float* g0, const float* e0, const float* g1,
                                           const float* e1, const float* cw, const float* rw,
                                           const float* t0, const float* t1, bf16* out) {
  if (i >= 108544) return;
  float v;
  if (i < 49152) {
    int which = i / 12288, r = i % 12288;
    const float* W = which == 0 ? g0 : which == 1 ? e0 : which == 2 ? g1 : e1;
    int l = r / 6144, j = r % 6144;
    int n = j / 96, k = j % 96;
    v = W[l * 6144 + k * 64 + n];
  } else if (i < 55296) {
    int j = i - 49152, n = j / 96, k = j % 96;
    v = cw[k * 64 + n];
  } else if (i < 59392) {
    int j = i - 55296, n = j / 64, k = j % 64;
    v = rw[k * 64 + n];
  } else {
    int r = i - 59392;
    int which = r / 24576;
    const float* W = which ? t1 : t0;
    int rr = r % 24576;
    int l = rr / 12288, j = rr % 12288;
    int ii = j & 63, o = (j >> 6) & 63, k = j >> 12;
    v = W[l * 12288 + o * 192 + ii * 3 + k];
  }
  out[i] = f2b(v);
}

__device__ __forceinline__ void enc_body(int idx, int din, const float* in, const float* W,
                                         const float* bias, bf16* out, float* last, int nodes) {
  if (idx >= G_ * nodes * 64) return;
  int d = idx & 63;
  int row = idx >> 6;
  int node = row % nodes;
  int g = row / nodes;
  const float* ir = in + (size_t)row * din;
  float acc = bias[d];
  for (int i = 0; i < din; i++) acc += ir[i] * W[i * 64 + d];
  if (g % T_ == T_ - 1) last[((size_t)(g / T_) * nodes + node) * 64 + d] = acc;
  out[idx] = f2b(fmaxf(acc, 0.f));
}

// ---------------- fused prologue: wprep + enc(x) + enc(e) ----------------
constexpr int NB_W = (108544 + 255) / 256;          // 424
constexpr int NB_EX = G_ * N_ * 64 / 256;           // 18000
constexpr int NB_EE = G_ * E_ * 64 / 256;           // 24000
__global__ __launch_bounds__(256) void k_begin(const float* __restrict__ g0, const float* __restrict__ e0,
                                               const float* __restrict__ g1, const float* __restrict__ e1,
                                               const float* __restrict__ cw, const float* __restrict__ rw,
                                               const float* __restrict__ t0, const float* __restrict__ t1,
                                               bf16* __restrict__ wAll,
                                               const float* __restrict__ x_in, const float* __restrict__ encxW,
                                               const float* __restrict__ encxB, bf16* __restrict__ xbuf,
                                               float* __restrict__ lastx,
                                               const float* __restrict__ e_in, const float* __restrict__ enceW,
                                               const float* __restrict__ enceB, bf16* __restrict__ ebuf,
                                               float* __restrict__ laste) {
  int bid = blockIdx.x, tid = threadIdx.x;
  if (bid < NB_W) {
    wprep_body(bid * 256 + tid, g0, e0, g1, e1, cw, rw, t0, t1, wAll);
  } else if (bid < NB_W + NB_EX) {
    enc_body((bid - NB_W) * 256 + tid, 4, x_in, encxW, encxB, xbuf, lastx, N_);
  } else {
    enc_body((bid - NB_W - NB_EX) * 256 + tid, 3, e_in, enceW, enceB, ebuf, laste, E_);
  }
}

// ---------------- encoders (conc phase, no SAVE) ----------------
template <int DIN, int DOUT>
__global__ __launch_bounds__(256) void k_enc2(const float* __restrict__ in, const float* __restrict__ W,
                                              const float* __restrict__ bias, bf16* __restrict__ out,
                                              int nodes) {
  int idx = blockIdx.x * 256 + threadIdx.x;
  if (idx >= G_ * nodes * DOUT) return;
  int d = idx % DOUT;
  int row = idx / DOUT;
  const float* ir = in + (size_t)row * DIN;
  float acc = bias[d];
#pragma unroll
  for (int i = 0; i < DIN; i++) acc += ir[i] * W[i * DOUT + d];
  out[idx] = f2b(fmaxf(acc, 0.f));
}

// ---------------- device body: fused NodeEdge linear + transpose ----------------
__device__ __forceinline__ void lin_neT_body(float* sh, int g, int n0, int t, const bf16* act,
                                             const float* W, const float* bias, bf16* outT,
                                             int nodes, int Kp) {
  float* As = sh;             // [64][65]
  float* Ws = sh + 4160;      // [2048]
  float* bs = sh + 4160 + 2048;
  for (int i = t; i < 2048; i += 256) Ws[i] = W[i];
  if (t < 32) bs[t] = bias[t];
  {
    int r = t >> 2, ch = t & 3;
    int node = n0 + r;
    short tmp[16];
    if (node < nodes) {
      const bf16* src = act + ((size_t)g * nodes + node) * 64 + ch * 16;
      *reinterpret_cast<uint4*>(tmp) = *reinterpret_cast<const uint4*>(src);
      *reinterpret_cast<uint4*>(tmp + 8) = *reinterpret_cast<const uint4*>(src + 8);
#pragma unroll
      for (int j = 0; j < 16; j++) As[r * 65 + ch * 16 + j] = b2f(*reinterpret_cast<bf16*>(&tmp[j]));
    } else {
#pragma unroll
      for (int j = 0; j < 16; j++) As[r * 65 + ch * 16 + j] = 0.f;
    }
  }
  __syncthreads();
  int nd = t & 63, fq = t >> 6;
  float acc[8];
#pragma unroll
  for (int j = 0; j < 8; j++) acc[j] = bs[fq * 8 + j];
  for (int i = 0; i < 64; i++) {
    float a = As[nd * 65 + i];
#pragma unroll
    for (int j = 0; j < 8; j++) acc[j] += a * Ws[i * 32 + fq * 8 + j];
  }
  bool valid = (n0 + nd) < nodes;
#pragma unroll
  for (int j = 0; j < 8; j++) {
    float v = valid ? fmaxf(acc[j], 0.f) : 0.f;
    outT[(size_t)(g * 32 + fq * 8 + j) * Kp + n0 + nd] = f2b(v);
  }
}

// ---------------- fused node-side prep: lin_neT(ebuf) || mat ----------------
constexpr int NBL_N = (KPN / 64) * G_;                   // 1536
constexpr int NBM_N = (N_ * KPN + 255) / 256;            // 12000
__global__ __launch_bounds__(256) void k_prepN(const bf16* __restrict__ act, const float* __restrict__ W,
                                               const float* __restrict__ bias, bf16* __restrict__ outT,
                                               const float* __restrict__ w, const float* __restrict__ p,
                                               const float* __restrict__ inci, bf16* __restrict__ mat) {
  __shared__ float sh[4160 + 2048 + 32];
  int bid = blockIdx.x, tid = threadIdx.x;
  if (bid < NBL_N) {
    lin_neT_body(sh, bid / (KPN / 64), (bid % (KPN / 64)) * 64, tid, act, W, bias, outT, E_, KPN);
  } else {
    int i = (bid - NBL_N) * 256 + tid;
    if (i < N_ * KPN) {
      int row = i / KPN, k = i % KPN;
      float v = 0.f;
      if (k < E_) {
        size_t o = (size_t)row * E_ + k;
        v = w[o] * fabsf(inci[o]) + p[o];
      }
      mat[i] = f2b(v);
    }
  }
}

// ---------------- fused edge-side prep: lin_neT(xbuf) || matT ----------------
constexpr int NBL_E = (KPE / 64) * G_;                   // 1152
constexpr int NBT_E = 63 * (KPE / 32);                   // 3024
__global__ __launch_bounds__(256) void k_prepE(const bf16* __restrict__ act, const float* __restrict__ W,
                                               const float* __restrict__ bias, bf16* __restrict__ outT,
                                               const float* __restrict__ w, const float* __restrict__ p,
                                               const float* __restrict__ inci, bf16* __restrict__ mat) {
  __shared__ float sh[4160 + 2048 + 32];
  int bid = blockIdx.x, tid = threadIdx.x;
  if (bid < NBL_E) {
    lin_neT_body(sh, bid / (KPE / 64), (bid % (KPE / 64)) * 64, tid, act, W, bias, outT, N_, KPE);
  } else {
    float* tl = sh;  // [32][33]
    int mt = bid - NBL_E;
    int e0 = (mt % 63) * 32, n0 = (mt / 63) * 32;
    int tx = tid & 31, ty = tid >> 5;
    for (int r = ty; r < 32; r += 8) {
      int n = n0 + r, e = e0 + tx;
      tl[r * 33 + tx] = (n < N_ && e < E_) ? fabsf(inci[(size_t)n * E_ + e]) : 0.f;
    }
    __syncthreads();
    for (int r = ty; r < 32; r += 8) {
      int e = e0 + r, n = n0 + tx;
      if (e < E_ && n < KPE) {
        size_t o = (size_t)e * N_ + n;
        mat[(size_t)e * KPE + n] = (n < N_) ? f2b(tl[tx * 33 + r] * w[o] + p[o]) : f2b(0.f);
      }
    }
  }
}

// ---------------- 64x128-tile MFMA GEMM, depth-4 pipeline + XCD swizzle (einsums) ----------
// Grid 1D, nwg%8==0; l=(bid&7)*(nwg/8)+bid>>3; bm=(l%gy)*64, bn=(l/gy)*128. 8 MFMA/phase/wave.
__global__ __launch_bounds__(256) void k_mgemm64(const bf16* __restrict__ A0, const bf16* __restrict__ Bt,
                                                 bf16* __restrict__ Cp, int Mm, int Kp, int Nn, int gy) {
  __shared__ __align__(16) short As[4][4][64][8];
  __shared__ __align__(16) short Bs[4][4][128][8];
  int tid = threadIdx.x;
  int nwg = gridDim.x;
  int bid = blockIdx.x;
  int l = (bid & 7) * (nwg >> 3) + (bid >> 3);
  int bm = (l % gy) * 64, bn = (l / gy) * 128;
  int lane = tid & 63, wid = tid >> 6;
  int wr = wid >> 1, wc = wid & 1;
  f32x4 acc[2][4];
#pragma unroll
  for (int i = 0; i < 2; i++)
#pragma unroll
    for (int j = 0; j < 4; j++) acc[i][j] = f32x4{0.f, 0.f, 0.f, 0.f};

  const int sr = tid >> 2;   // A stage row 0..63
  const int sc = tid & 3;    // A k-octet
  const int br = tid >> 1;   // B stage row 0..127
  const int bh = tid & 1;    // B 16-k half
  const int kb = lane >> 4, lr = lane & 15;
  const int gmA = bm + sr;
  const bool va_ok = (gmA < Mm);
  const bf16* ap = A0 + (size_t)gmA * Kp + sc * 8;
  const bf16* bp = Bt + (size_t)(bn + br) * Kp + bh * 16;
  const uint4 z4 = {0, 0, 0, 0};
  const int P = Kp >> 5;

  // prologue: ld(0)->L0, r1=ld(1), r2=ld(2)
  uint4 va0 = va_ok ? *reinterpret_cast<const uint4*>(ap) : z4;
  uint4 vb0a = *reinterpret_cast<const uint4*>(bp);
  uint4 vb0b = *reinterpret_cast<const uint4*>(bp + 8);
  uint4 va1 = va_ok ? *reinterpret_cast<const uint4*>(ap + 32) : z4;
  uint4 vb1a = *reinterpret_cast<const uint4*>(bp + 32);
  uint4 vb1b = *reinterpret_cast<const uint4*>(bp + 40);
  *reinterpret_cast<uint4*>(&As[0][sc][sr][0]) = va0;
  *reinterpret_cast<uint4*>(&Bs[0][bh * 2 + 0][br][0]) = vb0a;
  *reinterpret_cast<uint4*>(&Bs[0][bh * 2 + 1][br][0]) = vb0b;
  uint4 va2 = va_ok ? *reinterpret_cast<const uint4*>(ap + 64) : z4;
  uint4 vb2a = *reinterpret_cast<const uint4*>(bp + 64);
  uint4 vb2b = *reinterpret_cast<const uint4*>(bp + 72);
  __syncthreads();

  for (int p = 0; p < P; p += 2) {
    *reinterpret_cast<uint4*>(&As[(p + 1) & 3][sc][sr][0]) = va1;
    *reinterpret_cast<uint4*>(&Bs[(p + 1) & 3][bh * 2 + 0][br][0]) = vb1a;
    *reinterpret_cast<uint4*>(&Bs[(p + 1) & 3][bh * 2 + 1][br][0]) = vb1b;
    if (p + 3 < P) {
      va1 = va_ok ? *reinterpret_cast<const uint4*>(ap + (p + 3) * 32) : z4;
      vb1a = *reinterpret_cast<const uint4*>(bp + (p + 3) * 32);
      vb1b = *reinterpret_cast<const uint4*>(bp + (p + 3) * 32 + 8);
    }
    {
      int bf = p & 3;
      short8v a0 = *reinterpret_cast<const short8v*>(&As[bf][kb][wr * 32 + lr][0]);
      short8v a1 = *reinterpret_cast<const short8v*>(&As[bf][kb][wr * 32 + 16 + lr][0]);
      short8v b[4];
#pragma unroll
      for (int ni = 0; ni < 4; ni++)
        b[ni] = *reinterpret_cast<const short8v*>(&Bs[bf][kb][wc * 64 + ni * 16 + lr][0]);
      __builtin_amdgcn_s_setprio(1);
#pragma unroll
      for (int ni = 0; ni < 4; ni++) {
        acc[0][ni] = __builtin_amdgcn_mfma_f32_16x16x32_bf16(a0, b[ni], acc[0][ni], 0, 0, 0);
        acc[1][ni] = __builtin_amdgcn_mfma_f32_16x16x32_bf16(a1, b[ni], acc[1][ni], 0, 0, 0);
      }
      __builtin_amdgcn_s_setprio(0);
    }
    __syncthreads();
    *reinterpret_cast<uint4*>(&As[(p + 2) & 3][sc][sr][0]) = va2;
    *reinterpret_cast<uint4*>(&Bs[(p + 2) & 3][bh * 2 + 0][br][0]) = vb2a;
    *reinterpret_cast<uint4*>(&Bs[(p + 2) & 3][bh * 2 + 1][br][0]) = vb2b;
    if (p + 4 < P) {
      va2 = va_ok ? *reinterpret_cast<const uint4*>(ap + (p + 4) * 32) : z4;
      vb2a = *reinterpret_cast<const uint4*>(bp + (p + 4) * 32);
      vb2b = *reinterpret_cast<const uint4*>(bp + (p + 4) * 32 + 8);
    }
    {
      int bf = (p + 1) & 3;
      short8v a0 = *reinterpret_cast<const short8v*>(&As[bf][kb][wr * 32 + lr][0]);
      short8v a1 = *reinterpret_cast<const short8v*>(&As[bf][kb][wr * 32 + 16 + lr][0]);
      short8v b[4];
#pragma unroll
      for (int ni = 0; ni < 4; ni++)
        b[ni] = *reinterpret_cast<const short8v*>(&Bs[bf][kb][wc * 64 + ni * 16 + lr][0]);
      __builtin_amdgcn_s_setprio(1);
#pragma unroll
      for (int ni = 0; ni < 4; ni++) {
        acc[0][ni] = __builtin_amdgcn_mfma_f32_16x16x32_bf16(a0, b[ni], acc[0][ni], 0, 0, 0);
        acc[1][ni] = __builtin_amdgcn_mfma_f32_16x16x32_bf16(a1, b[ni], acc[1][ni], 0, 0, 0);
      }
      __builtin_amdgcn_s_setprio(0);
    }
    __syncthreads();
  }
#pragma unroll
  for (int mi = 0; mi < 2; mi++) {
    int r0 = bm + wr * 32 + mi * 16 + (lane >> 4) * 4;
#pragma unroll
    for (int ni = 0; ni < 4; ni++) {
      int col = bn + wc * 64 + ni * 16 + lr;
#pragma unroll
      for (int i = 0; i < 4; i++) {
        int r = r0 + i;
        if (r < Mm) Cp[(size_t)r * Nn + col] = f2b(acc[mi][ni][i]);
      }
    }
  }
}

// ---------------- single-stage MFMA GEMM for K<=96 (z / conc / res) ----------------
template <int AMODE, int KOCT, bool CF32b, bool ESED>
__global__ __launch_bounds__(256) void k_mgemm96(const bf16* __restrict__ A0, const bf16* __restrict__ A1,
                                                 const bf16* __restrict__ Bt, void* __restrict__ Cp,
                                                 int Mm, int nodes,
                                                 const float* __restrict__ bias, int relu,
                                                 const float* __restrict__ asv, const float* __restrict__ adv,
                                                 float* __restrict__ esOut, float* __restrict__ edOut) {
  constexpr int KP = KOCT * 8;
  __shared__ __align__(16) short As[KOCT][128][8];
  __shared__ __align__(16) short Bs[KOCT][64][8];
  __shared__ float smr[2][128][2];
  int tid = threadIdx.x;
  int bm = blockIdx.y * 128;
  int lane = tid & 63, wid = tid >> 6;
  int wr = wid >> 1, wc = wid & 1;
  const int kb = lane >> 4, lr = lane & 15;
  const uint4 z4 = {0, 0, 0, 0};

  {
    int ar = tid >> 1, ah = tid & 1;
    int gm = bm + ar;
    bool ok = (gm < Mm);
    int gdiv = 0, gmod = 0;
    if (AMODE == 1 && ok) { gdiv = gm / nodes; gmod = gm % nodes; }
#pragma unroll
    for (int c = 0; c < KOCT / 4; c++) {
      int ks = c * 32 + ah * 16;
      uint4 va0 = z4, va1 = z4;
      if (ok) {
        const bf16* src;
        if (AMODE == 0) src = A0 + (size_t)gm * KP + ks;
        else if (ks < 64) src = A0 + (size_t)gm * 64 + ks;
        else if (AMODE == 1) src = A1 + ((size_t)gmod * G_ + gdiv) * 32 + (ks - 64);
        else src = A1 + (size_t)gm * 32 + (ks - 64);
        const uint4* p = reinterpret_cast<const uint4*>(src);
        va0 = p[0];
        va1 = p[1];
      }
      *reinterpret_cast<uint4*>(&As[c * 4 + ah * 2 + 0][ar][0]) = va0;
      *reinterpret_cast<uint4*>(&As[c * 4 + ah * 2 + 1][ar][0]) = va1;
    }
  }
  {
    int br = tid >> 2, bk = tid & 3;
#pragma unroll
    for (int c = 0; c < KOCT / 4; c++) {
      int o = c * 4 + bk;
      uint4 vb = *reinterpret_cast<const uint4*>(Bt + (size_t)br * KP + o * 8);
      *reinterpret_cast<uint4*>(&Bs[o][br][0]) = vb;
    }
  }
  __syncthreads();

  f32x4 acc[4][2];
#pragma unroll
  for (int i = 0; i < 4; i++)
#pragma unroll
    for (int j = 0; j < 2; j++) acc[i][j] = f32x4{0.f, 0.f, 0.f, 0.f};

#pragma unroll
  for (int c = 0; c < KOCT / 4; c++) {
    short8v a[4], b[2];
#pragma unroll
    for (int mi = 0; mi < 4; mi++)
      a[mi] = *reinterpret_cast<const short8v*>(&As[c * 4 + kb][wr * 64 + mi * 16 + lr][0]);
#pragma unroll
    for (int ni = 0; ni < 2; ni++)
      b[ni] = *reinterpret_cast<const short8v*>(&Bs[c * 4 + kb][wc * 32 + ni * 16 + lr][0]);
    __builtin_amdgcn_s_setprio(1);
#pragma unroll
    for (int mi = 0; mi < 4; mi++)
#pragma unroll
      for (int ni = 0; ni < 2; ni++)
        acc[mi][ni] = __builtin_amdgcn_mfma_f32_16x16x32_bf16(a[mi], b[ni], acc[mi][ni], 0, 0, 0);
    __builtin_amdgcn_s_setprio(0);
  }

#pragma unroll
  for (int mi = 0; mi < 4; mi++) {
    int r0 = bm + wr * 64 + mi * 16 + (lane >> 4) * 4;
#pragma unroll
    for (int ni = 0; ni < 2; ni++) {
      int col = wc * 32 + ni * 16 + lr;
      float bv = bias ? bias[col] : 0.f;
#pragma unroll
      for (int i = 0; i < 4; i++) {
        int r = r0 + i;
        if (r < Mm) {
          float v = acc[mi][ni][i] + bv;
          if (relu) v = fmaxf(v, 0.f);
          if (CF32b) ((float*)Cp)[(size_t)r * 64 + col] = v;
          else ((bf16*)Cp)[(size_t)r * 64 + col] = f2b(v);
        }
      }
    }
  }
  if (ESED) {
    float asc0 = asv[wc * 32 + lr];
    float asc1 = asv[wc * 32 + 16 + lr];
    float adc0 = adv[wc * 32 + lr];
    float adc1 = adv[wc * 32 + 16 + lr];
#pragma unroll
    for (int mi = 0; mi < 4; mi++) {
#pragma unroll
      for (int i = 0; i < 4; i++) {
        float pe = acc[mi][0][i] * asc0 + acc[mi][1][i] * asc1;
        float pd = acc[mi][0][i] * adc0 + acc[mi][1][i] * adc1;
#pragma unroll
        for (int o = 8; o; o >>= 1) { pe += __shfl_xor(pe, o); pd += __shfl_xor(pd, o); }
        if (lr == 0) {
          int rl = wr * 64 + mi * 16 + (lane >> 4) * 4 + i;
          smr[wc][rl][0] = pe;
          smr[wc][rl][1] = pd;
        }
      }
    }
    __syncthreads();
    if (tid < 128) {
      int r = bm + tid;
      if (r < Mm) {
        esOut[r] = smr[0][tid][0] + smr[1][tid][0];
        edOut[r] = smr[0][tid][1] + smr[1][tid][1];
      }
    }
  }
}

// ---------------- causal dilated conv: merged x/e grids, depth-4 pipeline ----------------
template <int DIL>
__global__ __launch_bounds__(256) void k_cgemm2(const bf16* __restrict__ Ax, bf16* __restrict__ Cx,
                                                int Mx, int nx, const bf16* __restrict__ Ae,
                                                bf16* __restrict__ Ce, int Me, int ne, int nbx,
                                                const bf16* __restrict__ Wc, const float* __restrict__ bias) {
  __shared__ __align__(16) short As[4][4][128][8];
  int tid = threadIdx.x;
  int bid = blockIdx.x;
  const bf16* A;
  bf16* C;
  int Mm, nodes, bm;
  if (bid < nbx) { A = Ax; C = Cx; Mm = Mx; nodes = nx; bm = bid * 128; }
  else { A = Ae; C = Ce; Mm = Me; nodes = ne; bm = (bid - nbx) * 128; }
  int lane = tid & 63, wid = tid >> 6;
  int wr = wid >> 1, wc = wid & 1;
  const int ar = tid >> 1, ah = tid & 1;
  const int kb = lane >> 4, lr = lane & 15;
  const int gm = bm + ar;
  const int t = (gm / nodes) % T_;
  const uint4 z4 = {0, 0, 0, 0};

  short8v bfr[3][2][2];
#pragma unroll
  for (int tap = 0; tap < 3; tap++)
#pragma unroll
    for (int kc = 0; kc < 2; kc++)
#pragma unroll
      for (int ni = 0; ni < 2; ni++) {
        int col = wc * 32 + ni * 16 + lr;
        bfr[tap][kc][ni] = *reinterpret_cast<const short8v*>(Wc + tap * 4096 + (size_t)col * 64 + kc * 32 + kb * 8);
      }

  f32x4 acc[4][2];
#pragma unroll
  for (int i = 0; i < 4; i++)
#pragma unroll
    for (int j = 0; j < 2; j++) acc[i][j] = f32x4{0.f, 0.f, 0.f, 0.f};

#define CG_LDA(p, vx, vy)                                                          \
  {                                                                                \
    const int sh_ = (((p) >> 1) - 2) * DIL;                                        \
    if ((gm < Mm) && (t + sh_ >= 0)) {                                             \
      const uint4* pp = reinterpret_cast<const uint4*>(                            \
          A + ((size_t)gm + (size_t)sh_ * nodes) * 64 + ((p) & 1) * 32 + ah * 16); \
      vx = pp[0];                                                                  \
      vy = pp[1];                                                                  \
    } else {                                                                       \
      vx = z4;                                                                     \
      vy = z4;                                                                     \
    }                                                                              \
  }
#define CG_WR(buf, vx, vy)                                     \
  *reinterpret_cast<uint4*>(&As[buf][ah * 2 + 0][ar][0]) = vx; \
  *reinterpret_cast<uint4*>(&As[buf][ah * 2 + 1][ar][0]) = vy;
#define CG_MFMA(q)                                                                                         \
  {                                                                                                        \
    short8v a0_ = *reinterpret_cast<const short8v*>(&As[(q) & 3][kb][wr * 64 + 0 + lr][0]);                \
    short8v a1_ = *reinterpret_cast<const short8v*>(&As[(q) & 3][kb][wr * 64 + 16 + lr][0]);               \
    short8v a2_ = *reinterpret_cast<const short8v*>(&As[(q) & 3][kb][wr * 64 + 32 + lr][0]);               \
    short8v a3_ = *reinterpret_cast<const short8v*>(&As[(q) & 3][kb][wr * 64 + 48 + lr][0]);               \
    __builtin_amdgcn_s_setprio(1);                                                                         \
    acc[0][0] = __builtin_amdgcn_mfma_f32_16x16x32_bf16(a0_, bfr[(q) >> 1][(q) & 1][0], acc[0][0], 0, 0, 0); \
    acc[0][1] = __builtin_amdgcn_mfma_f32_16x16x32_bf16(a0_, bfr[(q) >> 1][(q) & 1][1], acc[0][1], 0, 0, 0); \
    acc[1][0] = __builtin_amdgcn_mfma_f32_16x16x32_bf16(a1_, bfr[(q) >> 1][(q) & 1][0], acc[1][0], 0, 0, 0); \
    acc[1][1] = __builtin_amdgcn_mfma_f32_16x16x32_bf16(a1_, bfr[(q) >> 1][(q) & 1][1], acc[1][1], 0, 0, 0); \
    acc[2][0] = __builtin_amdgcn_mfma_f32_16x16x32_bf16(a2_, bfr[(q) >> 1][(q) & 1][0], acc[2][0], 0, 0, 0); \
    acc[2][1] = __builtin_amdgcn_mfma_f32_16x16x32_bf16(a2_, bfr[(q) >> 1][(q) & 1][1], acc[2][1], 0, 0, 0); \
    acc[3][0] = __builtin_amdgcn_mfma_f32_16x16x32_bf16(a3_, bfr[(q) >> 1][(q) & 1][0], acc[3][0], 0, 0, 0); \
    acc[3][1] = __builtin_amdgcn_mfma_f32_16x16x32_bf16(a3_, bfr[(q) >> 1][(q) & 1][1], acc[3][1], 0, 0, 0); \
    __builtin_amdgcn_s_setprio(0);                                                                         \
  }
#define CG_BODY(p, lastPair)                  \
  CG_WR(((p) + 1) & 3, r1x, r1y);             \
  if (!(lastPair)) CG_LDA((p) + 3, r1x, r1y); \
  CG_MFMA(p);                                 \
  __syncthreads();                            \
  CG_WR(((p) + 2) & 3, r2x, r2y);             \
  if (!(lastPair)) CG_LDA((p) + 4, r2x, r2y); \
  CG_MFMA((p) + 1);                           \
  __syncthreads();

  uint4 p0x, p0y, r1x, r1y, r2x, r2y;
  CG_LDA(0, p0x, p0y);
  CG_LDA(1, r1x, r1y);
  CG_WR(0, p0x, p0y);
  CG_LDA(2, r2x, r2y);
  __syncthreads();

  CG_BODY(0, false)
  CG_BODY(2, false)
  CG_BODY(4, true)

#undef CG_LDA
#undef CG_WR
#undef CG_MFMA
#undef CG_BODY

#pragma unroll
  for (int mi = 0; mi < 4; mi++) {
    int r0 = bm + wr * 64 + mi * 16 + (lane >> 4) * 4;
#pragma unroll
    for (int ni = 0; ni < 2; ni++) {
      int col = wc * 32 + ni * 16 + lr;
      float bv = bias[col];
#pragma unroll
      for (int i = 0; i < 4; i++) {
        int r = r0 + i;
        if (r < Mm) C[(size_t)r * 64 + col] = f2b(fmaxf(acc[mi][ni][i] + bv, 0.f));
      }
    }
  }
}

// ---------------- GAT softmax weights ----------------
__global__ __launch_bounds__(256) void k_gat_w(const float* __restrict__ es, const float* __restrict__ edv,
                                               const int* __restrict__ off, const int* __restrict__ adj,
                                               float* __restrict__ wgt, int nodes, int tot) {
  int idx = blockIdx.x * 256 + threadIdx.x;
  if (idx >= G_ * nodes) return;
  int g = idx / nodes, node = idx % nodes;
  int s0 = off[node], s1 = off[node + 1];
  const float* esg = es + (size_t)g * nodes;
  float edval = edv[(size_t)g * nodes + node];
  float m = -FLT_MAX;
  for (int s = s0; s < s1; s++) {
    float a = esg[adj[s]] + edval;
    a = (a >= 0.f) ? a : 0.2f * a;
    m = fmaxf(m, a);
  }
  float den = 0.f;
  float* wg = wgt + (size_t)g * tot;
  for (int s = s0; s < s1; s++) {
    float a = esg[adj[s]] + edval;
    a = (a >= 0.f) ? a : 0.2f * a;
    float ex = expf(a - m);
    den += ex;
    wg[s] = ex;
  }
  float inv = (s1 > s0) ? 1.f / den : 0.f;
  for (int s = s0; s < s1; s++) wg[s] *= inv;
}

// ---------------- GAT aggregation ----------------
__global__ __launch_bounds__(256) void k_gat_aggr3(const bf16* __restrict__ z, const float* __restrict__ wgt,
                                                   const int* __restrict__ off, const int* __restrict__ adj,
                                                   const float* __restrict__ bias, bf16* __restrict__ out,
                                                   int nodes, int tot) {
  int idx = blockIdx.x * 256 + threadIdx.x;
  if (idx >= G_ * nodes * 16) return;
  int c = idx & 15;
  int rest = idx >> 4;
  int node = rest % nodes;
  int g = rest / nodes;
  int s0 = off[node], s1 = off[node + 1];
  const bf16* zg = z + (size_t)g * nodes * 64 + c * 4;
  const float* wg = wgt + (size_t)g * tot;
  float n0 = 0.f, n1 = 0.f, n2 = 0.f, n3 = 0.f;
  for (int s = s0; s < s1; s++) {
    int src = adj[s];
    float w = wg[s];
    bf16 v[4];
    *reinterpret_cast<uint2*>(v) = *reinterpret_cast<const uint2*>(zg + (size_t)src * 64);
    n0 += w * b2f(v[0]);
    n1 += w * b2f(v[1]);
    n2 += w * b2f(v[2]);
    n3 += w * b2f(v[3]);
  }
  bf16 ov[4];
  ov[0] = f2b(fmaxf(n0 + bias[c * 4 + 0], 0.f));
  ov[1] = f2b(fmaxf(n1 + bias[c * 4 + 1], 0.f));
  ov[2] = f2b(fmaxf(n2 + bias[c * 4 + 2], 0.f));
  ov[3] = f2b(fmaxf(n3 + bias[c * 4 + 3], 0.f));
  *reinterpret_cast<uint2*>(out + (size_t)rest * 64 + c * 4) = *reinterpret_cast<uint2*>(ov);
}

// ---------------- fused CSR build ----------------
__global__ __launch_bounds__(1024) void k_csr(const int* __restrict__ indN, const int* __restrict__ indE,
                                              int* __restrict__ offN, int* __restrict__ adjN,
                                              int* __restrict__ offE, int* __restrict__ adjE) {
  __shared__ int cnt[2048];
  __shared__ int a[1024];
  const int* ind;
  int ner, nn;
  int *off, *adj;
  if (blockIdx.x == 0) { ind = indN; ner = E_; nn = N_; off = offN; adj = adjN; }
  else { ind = indE; ner = M_; nn = E_; off = offE; adj = adjE; }
  int tot = ner + nn;
  int t = threadIdx.x;
  for (int i = t; i < nn; i += 1024) cnt[i] = 0;
  __syncthreads();
  for (int i = t; i < tot; i += 1024) {
    int d = (i < ner) ? ind[ner + i] : (i - ner);
    if (d >= 0 && d < nn) atomicAdd(&cnt[d], 1);
  }
  __syncthreads();
  int c0 = (2 * t < nn) ? cnt[2 * t] : 0;
  int c1 = (2 * t + 1 < nn) ? cnt[2 * t + 1] : 0;
  a[t] = c0 + c1;
  __syncthreads();
  for (int d = 1; d < 1024; d <<= 1) {
    int u = (t >= d) ? a[t - d] : 0;
    __syncthreads();
    a[t] += u;
    __syncthreads();
  }
  int excl = (t > 0) ? a[t - 1] : 0;
  if (2 * t < nn) { cnt[2 * t] = excl; off[2 * t] = excl; }
  if (2 * t + 1 < nn) { cnt[2 * t + 1] = excl + c0; off[2 * t + 1] = excl + c0; }
  if (t == 0) off[nn] = a[1023];
  __syncthreads();
  for (int i = t; i < tot; i += 1024) {
    int s, d;
    if (i < ner) { s = ind[i]; d = ind[ner + i]; }
    else { s = d = i - ner; }
    if (d >= 0 && d < nn) {
      int pos = atomicAdd(&cnt[d], 1);
      adj[pos] = s;
    }
  }
}

// ---------------- cumsum + residual + relu + head ----------------
template <bool XB>
__global__ __launch_bounds__(256) void k_out(const float* __restrict__ yx, const float* __restrict__ last,
                                             const float* __restrict__ oW, const float* __restrict__ ob_,
                                             float* __restrict__ dout, int nodes, int batches) {
  int wid = threadIdx.x >> 6, lane = threadIdx.x & 63;
  int idx = blockIdx.x * 4 + wid;
  if (idx >= batches * nodes) return;
  int b = idx / nodes, node = idx % nodes;
  const float* yb = yx + (size_t)b * T_ * nodes * 64;
  float lw = oW[lane];
  float ob = ob_[0];
  float lv = last[(size_t)idx * 64 + lane];
  float acc = 0.f;
  for (int tt = 0; tt < T_; tt++) {
    acc += yb[((size_t)tt * nodes + node) * 64 + lane];
    float v = fmaxf(acc + lv, 0.f);
    float p = v * lw;
#pragma unroll
    for (int o2 = 32; o2; o2 >>= 1) p += __shfl_down(p, o2);
    if (lane == 0) {
      float o = p + ob;
      if (XB) o = fminf(fmaxf(o / 6.f + 0.5f, 0.f), 1.f);
      else o = tanhf(o);
      dout[(size_t)b * T_ * nodes + (size_t)tt * nodes + node] = o;
    }
  }
}

// ===================================================================================
extern "C" void kernel_launch(void* const* d_in, const int* in_sizes, int n_in,
                              void* d_out, int out_size, void* d_ws, size_t ws_size,
                              hipStream_t stream) {
  float* dout = (float*)d_out;

  if (n_in != 57) {
    k_sentinel<<<ceilDiv(out_size, 256), 256, 0, stream>>>(dout, out_size, 20000.f + 128.f * n_in);
    return;
  }
  static const int expSz[57] = {
      288000, 288000, 288000, 288000,
      256, 64, 192, 64, 128, 32, 96, 32,
      3000000,
      12288, 128, 128, 128, 12288, 128, 128, 128,
      4096, 64, 6000000, 6000000, 4096, 64, 6000000, 6000000,
      24576, 128,
      12288, 128, 128, 128, 12288, 128, 128, 128,
      4096, 64, 6000000, 6000000, 4096, 64, 6000000, 6000000,
      24576, 128,
      6144, 64, 4096, 64, 64, 1, 4000, 8000};
  for (int i = 0; i < 57; i++) {
    if (in_sizes[i] != expSz[i]) {
      k_sentinel<<<ceilDiv(out_size, 256), 256, 0, stream>>>(dout, out_size, 4096.f + 64.f * i);
      return;
    }
  }

  auto ff = [&](int i) { return (const float*)d_in[i]; };
  const float *x_in = ff(0), *e_in = ff(1), *b_in = ff(2), *a_in = ff(3);
  const float *enc0W = ff(4), *enc0b = ff(5), *enc1W = ff(6), *enc1b = ff(7);
  const float *enc2W = ff(8), *enc2b = ff(9), *enc3W = ff(10), *enc3b = ff(11);
  const float* inci = ff(12);
  const float *concW = ff(49), *concb = ff(50), *resW = ff(51), *resb = ff(52);
  const float *outW = ff(53), *outb = ff(54);
  const int* edge_ind = (const int*)d_in[55];
  const int* node_ind = (const int*)d_in[56];

  // ---- workspace layout, 256B-aligned ----
  char* base = (char*)d_ws;
  size_t off = 0;
  auto A = [&](size_t bytes) { void* p = base + off; off = (off + bytes + 255) & ~(size_t)255; return p; };
  char* SCR = (char*)A(21504000);
  bf16* xbuf = (bf16*)A(9216000);
  bf16* ebuf = (bf16*)A(12288000);
  float* lastx = (float*)A(768000);
  float* laste = (float*)A(1024000);
  float* es = (float*)A(384000);
  float* edv = (float*)A(384000);
  float* wgt = (float*)A((size_t)G_ * (M_ + E_) * 4);
  bf16* wAll = (bf16*)A(217088);
  int* offN = (int*)A((N_ + 1) * 4);
  int* offE = (int*)A((E_ + 1) * 4);
  int* adjN = (int*)A((E_ + N_) * 4);
  int* adjE = (int*)A((M_ + E_) * 4);
  size_t required = off;

  if (ws_size < required) {
    k_sentinel<<<ceilDiv(out_size, 256), 256, 0, stream>>>(dout, out_size, 1000.f + (float)(ws_size >> 20));
    return;
  }

  // SCR aliases (liveness-checked)
  bf16* matb = (bf16*)SCR;
  bf16* tlinT = (bf16*)(SCR + 6553600);
  bf16* tmat = (bf16*)(SCR + 13107200);
  bf16* zbuf = (bf16*)SCR;
  bf16* bscr = (bf16*)SCR;
  bf16* cx1 = (bf16*)SCR;
  bf16* ce1 = (bf16*)(SCR + 9216000);
  float* zres = (float*)SCR;

  const int totN = E_ + N_;
  const int totE = M_ + E_;
  const int nbx = ceilDiv(G_ * N_, 128);  // 563
  const int nbe = ceilDiv(G_ * E_, 128);  // 750

  // ---- fused prologue (wprep + enc x + enc e) and CSR ----
  k_begin<<<NB_W + NB_EX + NB_EE, 256, 0, stream>>>(
      ff(13), ff(17), ff(31), ff(35), concW, resW, ff(29), ff(47), wAll,
      x_in, enc0W, enc0b, xbuf, lastx, e_in, enc1W, enc1b, ebuf, laste);
  k_csr<<<2, 1024, 0, stream>>>(edge_ind, node_ind, offN, adjN, offE, adjE);

  auto stblock = [&](int sb, int sbi) {
    const float *gxas = ff(sb + 1), *gxad = ff(sb + 2), *gxb = ff(sb + 3);
    const float *geas = ff(sb + 5), *gead = ff(sb + 6), *geb = ff(sb + 7);
    const float *neW = ff(sb + 8), *neb = ff(sb + 9), *nw = ff(sb + 10), *np_ = ff(sb + 11);
    const float *enW = ff(sb + 12), *enb = ff(sb + 13), *ew = ff(sb + 14), *ep = ff(sb + 15);
    const float* tpb = ff(sb + 17);
    for (int l = 0; l < 2; l++) {
      const bf16* gxw_t = wAll + sbi * 24576 + l * 6144;
      const bf16* gew_t = wAll + sbi * 24576 + 12288 + l * 6144;
      // ---- node side: fused lin_neT || mat, then einsum (64x128 tiles), z, gat ----
      k_prepN<<<NBL_N + NBM_N, 256, 0, stream>>>(ebuf, neW + l * 2048, neb + l * 32, tlinT,
                                                 nw + (size_t)l * N_ * E_, np_ + (size_t)l * N_ * E_, inci, matb);
      k_mgemm64<<<dim3(12 * 24), 256, 0, stream>>>(matb, tlinT, tmat, N_, KPN, 1536, 24);
      k_mgemm96<1, 12, false, true><<<dim3(1, nbx), 256, 0, stream>>>(
          xbuf, tmat, gxw_t, zbuf, G_ * N_, N_, nullptr, 0, gxas + l * 64, gxad + l * 64, es, edv);
      k_gat_w<<<ceilDiv(G_ * N_, 256), 256, 0, stream>>>(es, edv, offN, adjN, wgt, N_, totN);
      k_gat_aggr3<<<ceilDiv(G_ * N_ * 16, 256), 256, 0, stream>>>(zbuf, wgt, offN, adjN, gxb + l * 64, xbuf, N_, totN);
      // ---- edge side: fused lin_neT || matT, then einsum, z, gat ----
      k_prepE<<<NBL_E + NBT_E, 256, 0, stream>>>(xbuf, enW + l * 2048, enb + l * 32, tlinT,
                                                 ew + (size_t)l * E_ * N_, ep + (size_t)l * E_ * N_, inci, matb);
      k_mgemm64<<<dim3(12 * 32), 256, 0, stream>>>(matb, tlinT, tmat, E_, KPE, 1536, 32);
      k_mgemm96<1, 12, false, true><<<dim3(1, nbe), 256, 0, stream>>>(
          ebuf, tmat, gew_t, zbuf, G_ * E_, E_, nullptr, 0, geas + l * 64, gead + l * 64, es, edv);
      k_gat_w<<<ceilDiv(G_ * E_, 256), 256, 0, stream>>>(es, edv, offE, adjE, wgt, E_, totE);
      k_gat_aggr3<<<ceilDiv(G_ * E_ * 16, 256), 256, 0, stream>>>(zbuf, wgt, offE, adjE, geb + l * 64, ebuf, E_, totE);
    }
    // ---- temporal convs (merged x/e) ----
    const bf16* cw0 = wAll + 59392 + sbi * 24576;
    const bf16* cw1 = cw0 + 12288;
    k_cgemm2<1><<<nbx + nbe, 256, 0, stream>>>(xbuf, cx1, G_ * N_, N_, ebuf, ce1, G_ * E_, E_, nbx, cw0, tpb);
    k_cgemm2<2><<<nbx + nbe, 256, 0, stream>>>(cx1, xbuf, G_ * N_, N_, ce1, ebuf, G_ * E_, E_, nbx, cw1, tpb + 64);
  };

  stblock(13, 0);

  // ---- conc (shared weights; in-place: gridDim.x==1 row ownership) ----
  const bf16* concT = wAll + 49152;
  k_enc2<4, 32><<<ceilDiv(G_ * N_ * 32, 256), 256, 0, stream>>>(b_in, enc2W, enc2b, bscr, N_);
  k_mgemm96<2, 12, false, false><<<dim3(1, nbx), 256, 0, stream>>>(
      xbuf, bscr, concT, xbuf, G_ * N_, 0, concb, 1, nullptr, nullptr, nullptr, nullptr);
  k_enc2<3, 32><<<ceilDiv(G_ * E_ * 32, 256), 256, 0, stream>>>(a_in, enc3W, enc3b, bscr, E_);
  k_mgemm96<2, 12, false, false><<<dim3(1, nbe), 256, 0, stream>>>(
      ebuf, bscr, concT, ebuf, G_ * E_, 0, concb, 1, nullptr, nullptr, nullptr, nullptr);

  stblock(31, 1);

  // ---- final: N side in one pass, E side per batch ----
  const bf16* resT = wAll + 55296;
  k_mgemm96<0, 8, true, false><<<dim3(1, nbx), 256, 0, stream>>>(
      xbuf, nullptr, resT, zres, G_ * N_, 0, resb, 0, nullptr, nullptr, nullptr, nullptr);
  k_out<true><<<ceilDiv(B_ * N_, 4), 256, 0, stream>>>(zres, lastx, outW, outb, dout, N_, B_);
  for (int b = 0; b < B_; b++) {
    k_mgemm96<0, 8, true, false><<<dim3(1, ceilDiv(T_ * E_, 128)), 256, 0, stream>>>(
        ebuf + (size_t)b * T_ * E_ * 64, nullptr, resT, zres, T_ * E_, 0, resb, 0,
        nullptr, nullptr, nullptr, nullptr);
    k_out<false><<<ceilDiv(E_, 4), 256, 0, stream>>>(
        zres, laste + (size_t)b * E_ * 64, outW, outb, dout + (size_t)(B_ * T_ * N_) + (size_t)b * T_ * E_, E_, 1);
  }
}